// Round 7
// baseline (1127.258 us; speedup 1.0000x reference)
//
#include <hip/hip_runtime.h>
#include <hip/hip_fp16.h>
#include <math.h>

#define HDIM 128

typedef _Float16 f16x8 __attribute__((ext_vector_type(8)));
typedef float f32x4 __attribute__((ext_vector_type(4)));

struct alignas(8) half4 { __half2 lo, hi; };

__device__ __forceinline__ float4 h4_to_f4(half4 h) {
    float2 a = __half22float2(h.lo), b = __half22float2(h.hi);
    return make_float4(a.x, a.y, b.x, b.y);
}
__device__ __forceinline__ half4 f4_to_h4(float4 f) {
    half4 h;
    h.lo = __float22half2_rn(make_float2(f.x, f.y));
    h.hi = __float22half2_rn(make_float2(f.z, f.w));
    return h;
}
// nontemporal 8-byte edge load: (src, weight_bits)
__device__ __forceinline__ int2 ld_nt_int2(const int2* p) {
    long long v = __builtin_nontemporal_load((const long long*)p);
    int2 r; r.x = (int)(v & 0xffffffffLL); r.y = (int)(v >> 32); return r;
}

// ---------------- degree / CSR build ----------------

__global__ void degs_kernel(const int* __restrict__ src, const int* __restrict__ dst,
                            int* __restrict__ degS, int* __restrict__ degD, int E) {
    int e = blockIdx.x * blockDim.x + threadIdx.x;
    if (e < E) {
        atomicAdd(&degS[src[e]], 1);
        atomicAdd(&degD[dst[e]], 1);
    }
}

__global__ void dinv_kernel(const int* __restrict__ degS, float* __restrict__ dinv, int N) {
    int i = blockIdx.x * blockDim.x + threadIdx.x;
    if (i < N) { int d = degS[i]; dinv[i] = d > 0 ? rsqrtf((float)d) : 0.f; }
}

// single-block exclusive scan of degD -> rp[0..N], rp[N] = E
__global__ __launch_bounds__(1024)
void scan_kernel(const int* __restrict__ deg, int* __restrict__ rp, int N) {
    __shared__ int part[1024];
    int tid = threadIdx.x;
    int chunk = (N + 1023) / 1024;
    int start = tid * chunk;
    int end = start + chunk; if (end > N) end = N;
    int s = 0;
    for (int i = start; i < end; ++i) s += deg[i];
    part[tid] = s;
    __syncthreads();
    for (int off = 1; off < 1024; off <<= 1) {
        int v = (tid >= off) ? part[tid - off] : 0;
        __syncthreads();
        part[tid] += v;
        __syncthreads();
    }
    int run = (tid == 0) ? 0 : part[tid - 1];
    for (int i = start; i < end; ++i) { rp[i] = run; run += deg[i]; }
    if (start < N && end == N) rp[N] = run;
}

__global__ void scatter_kernel(const int* __restrict__ src, const int* __restrict__ dst,
                               const float* __restrict__ dinv, const int* __restrict__ rp,
                               int* __restrict__ cursor, int2* __restrict__ ev, int E) {
    int e = blockIdx.x * blockDim.x + threadIdx.x;
    if (e >= E) return;
    int s = src[e], d = dst[e];
    float w = -dinv[s] * dinv[d];
    int pos = atomicAdd(&cursor[d], 1);
    ev[rp[d] + pos] = make_int2(s, __float_as_int(w));
}

// sort each adjacency list by src (banding: concurrent waves sweep the node
// table in the same direction -> L2-resident hot band)
__global__ void sortadj_kernel(const int* __restrict__ rp, int2* __restrict__ ev, int N) {
    int node = blockIdx.x * blockDim.x + threadIdx.x;
    if (node >= N) return;
    int b = rp[node], e = rp[node + 1];
    for (int i = b + 1; i < e; ++i) {
        int2 key = ev[i];
        int j = i - 1;
        while (j >= b && ev[j].x > key.x) { ev[j + 1] = ev[j]; --j; }
        ev[j + 1] = key;
    }
}

// ---------------- pull propagation (fp16 tables, fp32 accumulate) ----------
template <int GBN, int PBN>
__global__ __launch_bounds__(256)
void pull128(const __half* __restrict__ t, const int* __restrict__ rp,
             const int2* __restrict__ ev, const __half* __restrict__ prev,
             const float* __restrict__ bnp, __half* __restrict__ outp,
             float alpha, int N) {
    int node = blockIdx.x * 4 + (threadIdx.x >> 6);
    if (node >= N) return;
    int lane = threadIdx.x & 63;
    int c4 = (lane & 31) * 4;     // channel group (4 channels, 8 B fp16)
    int epar = lane >> 5;         // edge parity for this half-wave

    float4 sc = make_float4(1.f, 1.f, 1.f, 1.f);
    float4 sh = make_float4(0.f, 0.f, 0.f, 0.f);
    if (GBN || PBN) {
        sc = *(const float4*)(bnp + c4);
        sh = *(const float4*)(bnp + 128 + c4);
    }

    int b = rp[node], e = rp[node + 1];
    float4 a0 = {0,0,0,0}, a1 = {0,0,0,0}, a2 = {0,0,0,0}, a3 = {0,0,0,0};

    int j = b;
    for (; j + 8 <= e; j += 8) {
        int2 s0 = ld_nt_int2(&ev[j + 0 + epar]);
        int2 s1 = ld_nt_int2(&ev[j + 2 + epar]);
        int2 s2 = ld_nt_int2(&ev[j + 4 + epar]);
        int2 s3 = ld_nt_int2(&ev[j + 6 + epar]);
        float4 r0 = h4_to_f4(*(const half4*)(t + (size_t)s0.x * HDIM + c4));
        float4 r1 = h4_to_f4(*(const half4*)(t + (size_t)s1.x * HDIM + c4));
        float4 r2 = h4_to_f4(*(const half4*)(t + (size_t)s2.x * HDIM + c4));
        float4 r3 = h4_to_f4(*(const half4*)(t + (size_t)s3.x * HDIM + c4));
        float w0 = __int_as_float(s0.y), w1 = __int_as_float(s1.y);
        float w2 = __int_as_float(s2.y), w3 = __int_as_float(s3.y);
        if (GBN) {
            r0.x = r0.x * sc.x + sh.x; r0.y = r0.y * sc.y + sh.y; r0.z = r0.z * sc.z + sh.z; r0.w = r0.w * sc.w + sh.w;
            r1.x = r1.x * sc.x + sh.x; r1.y = r1.y * sc.y + sh.y; r1.z = r1.z * sc.z + sh.z; r1.w = r1.w * sc.w + sh.w;
            r2.x = r2.x * sc.x + sh.x; r2.y = r2.y * sc.y + sh.y; r2.z = r2.z * sc.z + sh.z; r2.w = r2.w * sc.w + sh.w;
            r3.x = r3.x * sc.x + sh.x; r3.y = r3.y * sc.y + sh.y; r3.z = r3.z * sc.z + sh.z; r3.w = r3.w * sc.w + sh.w;
        }
        a0.x += w0 * r0.x; a0.y += w0 * r0.y; a0.z += w0 * r0.z; a0.w += w0 * r0.w;
        a1.x += w1 * r1.x; a1.y += w1 * r1.y; a1.z += w1 * r1.z; a1.w += w1 * r1.w;
        a2.x += w2 * r2.x; a2.y += w2 * r2.y; a2.z += w2 * r2.z; a2.w += w2 * r2.w;
        a3.x += w3 * r3.x; a3.y += w3 * r3.y; a3.z += w3 * r3.z; a3.w += w3 * r3.w;
    }
    for (; j + 2 <= e; j += 2) {
        int2 s0 = ld_nt_int2(&ev[j + epar]);
        float w0 = __int_as_float(s0.y);
        float4 r0 = h4_to_f4(*(const half4*)(t + (size_t)s0.x * HDIM + c4));
        if (GBN) {
            r0.x = r0.x * sc.x + sh.x; r0.y = r0.y * sc.y + sh.y; r0.z = r0.z * sc.z + sh.z; r0.w = r0.w * sc.w + sh.w;
        }
        a0.x += w0 * r0.x; a0.y += w0 * r0.y; a0.z += w0 * r0.z; a0.w += w0 * r0.w;
    }
    if (j < e && epar == 0) {
        int2 s0 = ld_nt_int2(&ev[j]);
        float w0 = __int_as_float(s0.y);
        float4 r0 = h4_to_f4(*(const half4*)(t + (size_t)s0.x * HDIM + c4));
        if (GBN) {
            r0.x = r0.x * sc.x + sh.x; r0.y = r0.y * sc.y + sh.y; r0.z = r0.z * sc.z + sh.z; r0.w = r0.w * sc.w + sh.w;
        }
        a1.x += w0 * r0.x; a1.y += w0 * r0.y; a1.z += w0 * r0.z; a1.w += w0 * r0.w;
    }

    float4 s4;
    s4.x = (a0.x + a1.x) + (a2.x + a3.x);
    s4.y = (a0.y + a1.y) + (a2.y + a3.y);
    s4.z = (a0.z + a1.z) + (a2.z + a3.z);
    s4.w = (a0.w + a1.w) + (a2.w + a3.w);
    s4.x += __shfl_xor(s4.x, 32);
    s4.y += __shfl_xor(s4.y, 32);
    s4.z += __shfl_xor(s4.z, 32);
    s4.w += __shfl_xor(s4.w, 32);

    if (lane < 32) {
        size_t o = (size_t)node * HDIM + c4;
        float4 r;
        r.x = alpha * s4.x; r.y = alpha * s4.y; r.z = alpha * s4.z; r.w = alpha * s4.w;
        if (!GBN) {
            float4 pv = h4_to_f4(*(const half4*)(prev + o));
            if (PBN) {
                pv.x = pv.x * sc.x + sh.x; pv.y = pv.y * sc.y + sh.y;
                pv.z = pv.z * sc.z + sh.z; pv.w = pv.w * sc.w + sh.w;
            }
            r.x -= pv.x; r.y -= pv.y; r.z -= pv.z; r.w -= pv.w;
        }
        *(half4*)(outp + o) = f4_to_h4(r);
    }
}

__global__ void pull3(const float* __restrict__ t, const float* __restrict__ prev,
                      const int* __restrict__ rp, const int2* __restrict__ ev,
                      float* __restrict__ outp, float alpha, int N) {
    int node = blockIdx.x * blockDim.x + threadIdx.x;
    if (node >= N) return;
    int b = rp[node], e = rp[node + 1];
    float a0 = 0.f, a1 = 0.f, a2 = 0.f;
    for (int j = b; j < e; ++j) {
        int2 sw = ev[j];
        float w = __int_as_float(sw.y);
        const float* r = t + (size_t)sw.x * 3;
        a0 += w * r[0]; a1 += w * r[1]; a2 += w * r[2];
    }
    float r0 = alpha * a0, r1 = alpha * a1, r2 = alpha * a2;
    if (prev) {
        r0 -= prev[node * 3 + 0];
        r1 -= prev[node * 3 + 1];
        r2 -= prev[node * 3 + 2];
    }
    outp[node * 3 + 0] = r0;
    outp[node * 3 + 1] = r1;
    outp[node * 3 + 2] = r2;
}

// ---------------- weight prep: fold BN(T0) into W, transpose, fp16 --------
__global__ void wprep_kernel(const float* __restrict__ W, const float* __restrict__ bnp,
                             _Float16* __restrict__ Wt) {
    int idx = blockIdx.x * 256 + threadIdx.x;   // 65536
    int n = idx >> 9, sk = idx & 511;
    int sel = sk >> 7, k = sk & 127;
    float v = W[sel * 16384 + k * 128 + n];
    if (sel == 0) v *= bnp[k];
    Wt[idx] = (_Float16)v;
}

// bias2[n] = b[n] + sum_k bnp_shift[k] * W[0][k][n]
__global__ void bias2_kernel(const float* __restrict__ W, const float* __restrict__ bnp,
                             const float* __restrict__ b, float* __restrict__ bias2) {
    int n = threadIdx.x;
    float s = b[n];
    for (int k = 0; k < 128; ++k) s += bnp[128 + k] * W[k * 128 + n];
    bias2[n] = s;
}

// ---------------- MFMA Cheb GEMM -------------------------------------------
// per kt: batch 8 A-loads (4 sel x 2 row-frags, HBM) + 16 B-frags (L2),
// then 32 MFMAs. 8x more memory parallelism than round-6 version.
template <int ACT, int STATS, int OUTH>
__global__ __launch_bounds__(256)
void gemm_mfma(const __half* __restrict__ T0, const __half* __restrict__ T1,
               const __half* __restrict__ T2, const __half* __restrict__ T3,
               const _Float16* __restrict__ Wt, const float* __restrict__ bias2,
               __half* __restrict__ outh, float* __restrict__ outf,
               float* __restrict__ stats, int N) {
    __shared__ float s_sum[128];
    __shared__ float s_sq[128];
    int tid = threadIdx.x;
    if (STATS) {
        if (tid < 128) { s_sum[tid] = 0.f; s_sq[tid] = 0.f; }
        __syncthreads();
    }
    int wave = tid >> 6, lane = tid & 63;
    int wr = wave >> 1, wc = wave & 1;
    int m = lane & 15, quad = lane >> 4;
    int row0 = blockIdx.x * 64 + wr * 32;

    size_t ra0 = (size_t)(min(row0 + m, N - 1)) * HDIM;
    size_t ra1 = (size_t)(min(row0 + 16 + m, N - 1)) * HDIM;

    const __half* Ts[4] = {T0, T1, T2, T3};
    f32x4 acc[2][4];
#pragma unroll
    for (int rt = 0; rt < 2; ++rt)
#pragma unroll
        for (int ct = 0; ct < 4; ++ct) acc[rt][ct] = (f32x4){0.f, 0.f, 0.f, 0.f};

    const _Float16* Wn = Wt + (size_t)(wc * 64 + m) * 512;   // row n = wc*64+ct*16+m

#pragma unroll
    for (int kt = 0; kt < 4; ++kt) {
        int ko = kt * 32 + quad * 8;
        f16x8 a0[4], a1[4];
#pragma unroll
        for (int sel = 0; sel < 4; ++sel) {
            const _Float16* Tp = (const _Float16*)Ts[sel];
            a0[sel] = *(const f16x8*)(Tp + ra0 + ko);
            a1[sel] = *(const f16x8*)(Tp + ra1 + ko);
        }
        f16x8 bf[4][4];
#pragma unroll
        for (int sel = 0; sel < 4; ++sel) {
            const _Float16* Wb = Wn + sel * 128 + ko;
#pragma unroll
            for (int ct = 0; ct < 4; ++ct)
                bf[sel][ct] = *(const f16x8*)(Wb + (size_t)ct * 16 * 512);
        }
#pragma unroll
        for (int sel = 0; sel < 4; ++sel) {
#pragma unroll
            for (int ct = 0; ct < 4; ++ct) {
                acc[0][ct] = __builtin_amdgcn_mfma_f32_16x16x32_f16(a0[sel], bf[sel][ct], acc[0][ct], 0, 0, 0);
                acc[1][ct] = __builtin_amdgcn_mfma_f32_16x16x32_f16(a1[sel], bf[sel][ct], acc[1][ct], 0, 0, 0);
            }
        }
    }

    // epilogue: D tile (rt,ct): row = row0 + rt*16 + quad*4 + r, col = wc*64 + ct*16 + m
    float csum[4] = {}, csq[4] = {};
#pragma unroll
    for (int ct = 0; ct < 4; ++ct) {
        int col = wc * 64 + ct * 16 + m;
        float bv = bias2[col];
#pragma unroll
        for (int rt = 0; rt < 2; ++rt) {
#pragma unroll
            for (int r = 0; r < 4; ++r) {
                int drow = row0 + rt * 16 + quad * 4 + r;
                if (drow < N) {
                    float v = acc[rt][ct][r] + bv;
                    if (ACT == 1) v = v >= 0.f ? v : 0.01f * v;
                    else if (ACT == 2) v = fmaxf(v, 0.f);
                    if (OUTH) outh[(size_t)drow * HDIM + col] = __float2half(v);
                    else      outf[(size_t)drow * HDIM + col] = v;
                    if (STATS) { csum[ct] += v; csq[ct] += v * v; }
                }
            }
        }
    }
    if (STATS) {
#pragma unroll
        for (int ct = 0; ct < 4; ++ct) {
            int col = wc * 64 + ct * 16 + m;
            atomicAdd(&s_sum[col], csum[ct]);
            atomicAdd(&s_sq[col], csq[ct]);
        }
        __syncthreads();
        if (tid < 128) {
            atomicAdd(&stats[tid], s_sum[tid]);
            atomicAdd(&stats[128 + tid], s_sq[tid]);
        }
    }
}

// ---------------- layer-1 (input dim 3) fused GEMM, grid-stride ----------------
__global__ __launch_bounds__(256)
void gemm1_kernel(const float* __restrict__ x, const float* __restrict__ t1,
                  const float* __restrict__ t2, const float* __restrict__ t3,
                  const float* __restrict__ W1, const float* __restrict__ b1,
                  __half* __restrict__ out, float* __restrict__ stats, int N) {
    __shared__ float s_sum[128];
    __shared__ float s_sq[128];
    int tid = threadIdx.x;
    int c = tid & 127;
    if (tid < 128) { s_sum[tid] = 0.f; s_sq[tid] = 0.f; }
    __syncthreads();
    float wreg[12];
#pragma unroll
    for (int i = 0; i < 12; ++i) wreg[i] = W1[i * 128 + c];
    float bias = b1[c];
    const float* Ts[4] = {x, t1, t2, t3};
    float lsum = 0.f, lsq = 0.f;
    for (int row = blockIdx.x * 2 + (tid >> 7); row < N; row += gridDim.x * 2) {
        float v = bias;
#pragma unroll
        for (int k = 0; k < 4; ++k) {
            const float* t = Ts[k];
#pragma unroll
            for (int d = 0; d < 3; ++d)
                v += t[row * 3 + d] * wreg[k * 3 + d];
        }
        v = v >= 0.f ? v : 0.01f * v;   // leaky_relu
        out[(size_t)row * HDIM + c] = __float2half(v);
        lsum += v; lsq += v * v;
    }
    atomicAdd(&s_sum[c], lsum);
    atomicAdd(&s_sq[c], lsq);
    __syncthreads();
    if (tid < 128) {
        atomicAdd(&stats[tid], s_sum[tid]);
        atomicAdd(&stats[128 + tid], s_sq[tid]);
    }
}

// ---------------- BN finalize: stats -> (scale, shift) ----------------
__global__ void bnfin_kernel(const float* __restrict__ stats, const float* __restrict__ g,
                             const float* __restrict__ be, float* __restrict__ bnp, float invN) {
    int c = threadIdx.x;  // 128 threads
    float m = stats[c] * invN;
    float v = stats[128 + c] * invN - m * m;
    float sc = g[c] * rsqrtf(v + 1e-5f);
    bnp[c] = sc;
    bnp[128 + c] = be[c] - m * sc;
}

// ---------------- final: L2-normalize row + project to 3 ----------------
__global__ void final_kernel(const float* __restrict__ Z, const float* __restrict__ Wm,
                             const float* __restrict__ bm, float* __restrict__ out, int N) {
    int gid = blockIdx.x * blockDim.x + threadIdx.x;
    int node = gid >> 6;
    int lane = threadIdx.x & 63;
    if (node >= N) return;
    const float* z = Z + (size_t)node * HDIM;
    float z0 = z[lane], z1 = z[lane + 64];
    float sq = z0 * z0 + z1 * z1;
    float d0 = z0 * Wm[lane * 3 + 0] + z1 * Wm[(lane + 64) * 3 + 0];
    float d1 = z0 * Wm[lane * 3 + 1] + z1 * Wm[(lane + 64) * 3 + 1];
    float d2 = z0 * Wm[lane * 3 + 2] + z1 * Wm[(lane + 64) * 3 + 2];
#pragma unroll
    for (int off = 32; off > 0; off >>= 1) {
        sq += __shfl_down(sq, off);
        d0 += __shfl_down(d0, off);
        d1 += __shfl_down(d1, off);
        d2 += __shfl_down(d2, off);
    }
    if (lane == 0) {
        float inv = 1.f / fmaxf(sqrtf(sq), 1e-12f);
        out[node * 3 + 0] = d0 * inv + bm[0];
        out[node * 3 + 1] = d1 * inv + bm[1];
        out[node * 3 + 2] = d2 * inv + bm[2];
    }
}

// ---------------- host ----------------

extern "C" void kernel_launch(void* const* d_in, const int* in_sizes, int n_in,
                              void* d_out, int out_size, void* d_ws, size_t ws_size,
                              hipStream_t stream) {
    const float* x  = (const float*)d_in[0];
    const int*   ei = (const int*)d_in[1];
    const float* W1 = (const float*)d_in[2];
    const float* b1 = (const float*)d_in[3];
    const float* W2 = (const float*)d_in[4];
    const float* b2 = (const float*)d_in[5];
    const float* W3 = (const float*)d_in[6];
    const float* b3 = (const float*)d_in[7];
    const float* W4 = (const float*)d_in[8];
    const float* b4 = (const float*)d_in[9];
    const float* g1 = (const float*)d_in[10];
    const float* be1 = (const float*)d_in[11];
    const float* g2 = (const float*)d_in[12];
    const float* be2 = (const float*)d_in[13];
    const float* g3 = (const float*)d_in[14];
    const float* be3 = (const float*)d_in[15];
    const float* Wm = (const float*)d_in[16];
    const float* bm = (const float*)d_in[17];
    float* out = (float*)d_out;

    const int N = in_sizes[0] / 3;
    const int E = in_sizes[1] / 2;
    const size_t NH = (size_t)N * HDIM;
    const int* src = ei;
    const int* dst = ei + E;

    // ---- workspace layout ----
    char* base = (char*)d_ws;
    int* degS   = (int*)base;            base += (size_t)N * 4;
    int* degD   = (int*)base;            base += (size_t)N * 4;
    int* cursor = (int*)base;            base += (size_t)N * 4;
    int* rp     = (int*)base;            base += (size_t)(N + 2) * 4;
    int2* ev    = (int2*)base;           base += (size_t)E * 8;
    float* dinv = (float*)base;          base += (size_t)N * 4;
    __half* Za  = (__half*)base;         base += NH * 2;
    __half* Zb  = (__half*)base;         base += NH * 2;
    __half* T1  = (__half*)base;         base += NH * 2;
    __half* T2  = (__half*)base;         base += NH * 2;
    __half* T3  = (__half*)base;         base += NH * 2;
    float* Zf   = (float*)base;          base += NH * 4;   // layer-4 out, fp32
    float* x1   = (float*)base;          base += (size_t)N * 3 * 4;
    float* x2   = (float*)base;          base += (size_t)N * 3 * 4;
    float* x3   = (float*)base;          base += (size_t)N * 3 * 4;
    float* stats = (float*)base;         base += 256 * 4;
    float* bnp1  = (float*)base;         base += 256 * 4;
    float* bnp2  = (float*)base;         base += 256 * 4;
    float* bnp3  = (float*)base;         base += 256 * 4;
    _Float16* Wt = (_Float16*)base;      base += (size_t)65536 * 2;
    float* bias2 = (float*)base;         base += 128 * 4;

    const int EB = (E + 255) / 256;
    const int NB = (N + 255) / 256;
    const int GB = (N + 63) / 64;         // mfma gemm row tiles
    const int PB = (N + 3) / 4;           // pull128 blocks (4 nodes/block)
    const float invN = 1.f / (float)N;

    // --- CSR build + edge weights ---
    hipMemsetAsync(degS, 0, (size_t)N * 3 * 4, stream);   // degS, degD, cursor
    degs_kernel<<<EB, 256, 0, stream>>>(src, dst, degS, degD, E);
    dinv_kernel<<<NB, 256, 0, stream>>>(degS, dinv, N);
    scan_kernel<<<1, 1024, 0, stream>>>(degD, rp, N);
    scatter_kernel<<<EB, 256, 0, stream>>>(src, dst, dinv, rp, cursor, ev, E);
    sortadj_kernel<<<NB, 256, 0, stream>>>(rp, ev, N);

    // --- layer 1 (dim 3) -> Za (fp16), bnp1 ---
    pull3<<<NB, 256, 0, stream>>>(x,  nullptr, rp, ev, x1, 1.f, N);
    pull3<<<NB, 256, 0, stream>>>(x1, x,       rp, ev, x2, 2.f, N);
    pull3<<<NB, 256, 0, stream>>>(x2, x1,      rp, ev, x3, 2.f, N);
    hipMemsetAsync(stats, 0, 256 * 4, stream);
    gemm1_kernel<<<512, 256, 0, stream>>>(x, x1, x2, x3, W1, b1, Za, stats, N);
    bnfin_kernel<<<1, 128, 0, stream>>>(stats, g1, be1, bnp1, invN);

    // --- layer 2 (leaky + BN): input BN(Za,bnp1) -> Zb, bnp2 ---
    wprep_kernel<<<256, 256, 0, stream>>>(W2, bnp1, Wt);
    bias2_kernel<<<1, 128, 0, stream>>>(W2, bnp1, b2, bias2);
    pull128<1, 0><<<PB, 256, 0, stream>>>(Za, rp, ev, nullptr, bnp1, T1, 1.f, N);
    pull128<0, 1><<<PB, 256, 0, stream>>>(T1, rp, ev, Za, bnp1, T2, 2.f, N);
    pull128<0, 0><<<PB, 256, 0, stream>>>(T2, rp, ev, T1, nullptr, T3, 2.f, N);
    hipMemsetAsync(stats, 0, 256 * 4, stream);
    gemm_mfma<1, 1, 1><<<GB, 256, 0, stream>>>(Za, T1, T2, T3, Wt, bias2, Zb, nullptr, stats, N);
    bnfin_kernel<<<1, 128, 0, stream>>>(stats, g2, be2, bnp2, invN);

    // --- layer 3 (relu + BN): input BN(Zb,bnp2) -> Za, bnp3 ---
    wprep_kernel<<<256, 256, 0, stream>>>(W3, bnp2, Wt);
    bias2_kernel<<<1, 128, 0, stream>>>(W3, bnp2, b3, bias2);
    pull128<1, 0><<<PB, 256, 0, stream>>>(Zb, rp, ev, nullptr, bnp2, T1, 1.f, N);
    pull128<0, 1><<<PB, 256, 0, stream>>>(T1, rp, ev, Zb, bnp2, T2, 2.f, N);
    pull128<0, 0><<<PB, 256, 0, stream>>>(T2, rp, ev, T1, nullptr, T3, 2.f, N);
    hipMemsetAsync(stats, 0, 256 * 4, stream);
    gemm_mfma<2, 1, 1><<<GB, 256, 0, stream>>>(Zb, T1, T2, T3, Wt, bias2, Za, nullptr, stats, N);
    bnfin_kernel<<<1, 128, 0, stream>>>(stats, g3, be3, bnp3, invN);

    // --- layer 4 (no act/BN): input BN(Za,bnp3) -> Zf (fp32) ---
    wprep_kernel<<<256, 256, 0, stream>>>(W4, bnp3, Wt);
    bias2_kernel<<<1, 128, 0, stream>>>(W4, bnp3, b4, bias2);
    pull128<1, 0><<<PB, 256, 0, stream>>>(Za, rp, ev, nullptr, bnp3, T1, 1.f, N);
    pull128<0, 1><<<PB, 256, 0, stream>>>(T1, rp, ev, Za, bnp3, T2, 2.f, N);
    pull128<0, 0><<<PB, 256, 0, stream>>>(T2, rp, ev, T1, nullptr, T3, 2.f, N);
    gemm_mfma<0, 0, 0><<<GB, 256, 0, stream>>>(Za, T1, T2, T3, Wt, bias2, nullptr, Zf, nullptr, N);

    // --- normalize + project ---
    final_kernel<<<(N * 64 + 255) / 256, 256, 0, stream>>>(Zf, Wm, bm, out, N);
}